// Round 18
// baseline (129.779 us; speedup 1.0000x reference)
//
#include <hip/hip_runtime.h>
#include <stdint.h>

#define B_SZ    8
#define N_PTS   4096
#define C_IN    64
#define C_OUT   64
#define KNN     16
#define ROWS    (B_SZ * N_PTS)      // 32768
#define NBLK_B  128                 // blocks per batch (32 rows each)

typedef __attribute__((ext_vector_type(8))) short v8s;   // 8 bf16 (4 VGPR)
typedef __attribute__((ext_vector_type(4))) float v4f;   // MFMA acc

__device__ inline unsigned short f2bf(float f) {         // RNE f32->bf16
    unsigned int u = __float_as_uint(f);
    return (unsigned short)((u + 0x7FFFu + ((u >> 16) & 1u)) >> 16);
}

__device__ inline v8s pack8(float4 q0, float4 q1) {
    v8s a;
    a[0] = (short)f2bf(q0.x); a[1] = (short)f2bf(q0.y);
    a[2] = (short)f2bf(q0.z); a[3] = (short)f2bf(q0.w);
    a[4] = (short)f2bf(q1.x); a[5] = (short)f2bf(q1.y);
    a[6] = (short)f2bf(q1.z); a[7] = (short)f2bf(q1.w);
    return a;
}

#define WPITCH 132   // fp32 pitch for staged w: (4*col)%32 spreads banks (2-way free)
#define PITCH  68

// ---------------------------------------------------------------------------
// SINGLE fused kernel. Grid 1024 = 256 CUs x 4 blocks (co-resident by
// __launch_bounds__(256,4): VGPR<=128, LDS 33KB -> 4 blocks/CU guaranteed).
//  1. stage w (32KB, L2-hot) -> LDS [64][WPITCH]; build bC=(W1-W2), bN=W2
//     frags per wave (fp32 subtract, RNE pack — same numerics as wprep).
//  2. stage 32 x-rows into sm (reuses the same LDS); MFMA:
//     cbuf tile -> LDS only; nbuf = x·W2 -> global bf16.
//  3. per-batch grid barrier: threadfence (L2 wb) + atomicAdd + bounded spin
//     + threadfence (L2 inv).  128 arrivals per counter.
//  4. gather nbuf rows (L2), max, +cbuf, relu, transposed store.
// ---------------------------------------------------------------------------
__global__ __launch_bounds__(256, 4) void fused_kernel(
    const float* __restrict__ x,
    const float* __restrict__ w,
    const float* __restrict__ bias,
    const int* __restrict__ eidx,
    unsigned short* __restrict__ nbuf,
    int* __restrict__ ctr,
    float* __restrict__ out)
{
    __shared__ float wl[C_OUT * WPITCH];    // 33 KiB; later reused as sm
    float (*sm)[PITCH] = (float(*)[PITCH])wl;

    const int t    = threadIdx.x;
    const int lane = t & 63;
    const int wv   = t >> 6;                // wave 0..3
    const int b    = blockIdx.x & 7;        // batch == XCD affinity
    const int tn   = blockIdx.x >> 3;       // 0..127
    const int n0   = tn * 32;
    const int r0g  = b * N_PTS + n0;

    // ---- prefetch eidx (phase-4 rows wv*8 .. +7) ----
    const size_t ebase = (size_t)(r0g + wv * 8) * KNN;
    const int pa = eidx[ebase + lane]      & (N_PTS - 1);
    const int pb = eidx[ebase + 64 + lane] & (N_PTS - 1);

    // ---- 1a. stage w into LDS (coalesced: thread t owns floats t*32..+31) ----
    {
        const float4* wsrc = (const float4*)w;
        const int colw = t >> 2;
        const int kqw  = (t & 3) * 32;
#pragma unroll
        for (int i = 0; i < 8; ++i)
            *(float4*)&wl[colw * WPITCH + kqw + i * 4] = wsrc[t * 8 + i];
    }
    __syncthreads();

    // ---- 1b. build B-frags from LDS ----
    const int rq   = wv & 1;                // row half for proj
    const int ch   = wv >> 1;               // col half for proj
    const int fc   = lane & 15;
    const int koff = 8 * (lane >> 4);
    v8s bC[2][2], bN[2][2];
#pragma unroll
    for (int ct = 0; ct < 2; ++ct) {
        const int col = ch * 32 + ct * 16 + fc;
#pragma unroll
        for (int ks = 0; ks < 2; ++ks) {
            const float* p1 = &wl[col * WPITCH + ks * 32 + koff];   // W1
            const float* p2 = p1 + 64;                              // W2
            const float4 a0 = *(const float4*)p1, a1 = *(const float4*)(p1 + 4);
            const float4 b0 = *(const float4*)p2, b1 = *(const float4*)(p2 + 4);
            bC[ct][ks] = pack8(
                make_float4(a0.x - b0.x, a0.y - b0.y, a0.z - b0.z, a0.w - b0.w),
                make_float4(a1.x - b1.x, a1.y - b1.y, a1.z - b1.z, a1.w - b1.w));
            bN[ct][ks] = pack8(b0, b1);
        }
    }
    __syncthreads();                        // wl reads done; reuse as sm

    // ---- 2a. stage 32 x-rows (8 KB) coalesced ----
    {
        const float4* xsrc = (const float4*)(x + (size_t)r0g * C_IN);
#pragma unroll
        for (int i = 0; i < 2; ++i) {
            const int idx = i * 256 + t;
            *(float4*)&sm[idx >> 4][(idx & 15) * 4] = xsrc[idx];
        }
    }
    __syncthreads();

    // ---- 2b. proj MFMA: cbuf (LDS) + nbuf (global bf16) ----
    const int rl0 = rq * 16;
    const int rl  = rl0 + fc;
    v8s af[2];
#pragma unroll
    for (int ks = 0; ks < 2; ++ks) {
        const float* xp = &sm[rl][ks * 32 + koff];
        af[ks] = pack8(*(const float4*)xp, *(const float4*)(xp + 4));
    }

    v4f accC[2], accN[2];
#pragma unroll
    for (int ct = 0; ct < 2; ++ct) {
        const float bv = bias[ch * 32 + ct * 16 + fc];
        accC[ct] = (v4f){bv, bv, bv, bv};
        accN[ct] = (v4f){0.f, 0.f, 0.f, 0.f};
    }
#pragma unroll
    for (int ks = 0; ks < 2; ++ks)
#pragma unroll
        for (int ct = 0; ct < 2; ++ct) {
            accC[ct] = __builtin_amdgcn_mfma_f32_16x16x32_bf16(
                af[ks], bC[ct][ks], accC[ct], 0, 0, 0);
            accN[ct] = __builtin_amdgcn_mfma_f32_16x16x32_bf16(
                af[ks], bN[ct][ks], accN[ct], 0, 0, 0);
        }

    // nbuf stores (global; drain before fence)
    const int orow = rl0 + (lane >> 4) * 4;
#pragma unroll
    for (int ct = 0; ct < 2; ++ct)
#pragma unroll
        for (int reg = 0; reg < 4; ++reg)
            nbuf[(size_t)(r0g + orow + reg) * C_OUT + ch * 32 + ct * 16 + fc] =
                f2bf(accN[ct][reg]);

    __syncthreads();                        // all af reads from sm done
#pragma unroll
    for (int ct = 0; ct < 2; ++ct)
#pragma unroll
        for (int reg = 0; reg < 4; ++reg)
            sm[orow + reg][ch * 32 + ct * 16 + fc] = accC[ct][reg];

    __syncthreads();                        // cbuf tile complete (+ stores drained)

    // ---- 3. per-batch grid barrier (manual, bounded spin) ----
    if (t == 0) {
        __threadfence();                    // release: L2 writeback of nbuf
        atomicAdd(&ctr[b], 1);              // device-scope RMW at PoC
        int guard = 1 << 22;                // bounded: fail->wrong, not hang
        while (guard-- > 0 &&
               __hip_atomic_load(&ctr[b], __ATOMIC_RELAXED,
                                 __HIP_MEMORY_SCOPE_AGENT) < NBLK_B)
            __builtin_amdgcn_s_sleep(1);
        __threadfence();                    // acquire: L2 invalidate
    }
    __syncthreads();

    // ---- 4. gather + max + relu (wave wv: rows wv*8..+7) ----
    const unsigned short* nb = nbuf + (size_t)b * N_PTS * C_OUT;
    const int o4  = (lane & 15) * 4;
    const int sub = lane >> 4;

#pragma unroll
    for (int i = 0; i < 2; ++i) {
        const int rbl   = wv * 8 + i * 4;
        const int myidx = (i == 0) ? pa : pb;

        const float4 cv = *(const float4*)&sm[rbl + sub][o4];

        float m0 = -1e30f, m1 = -1e30f, m2 = -1e30f, m3 = -1e30f;
#pragma unroll
        for (int k = 0; k < KNN; ++k) {
            const int idx = __shfl(myidx, (lane & 48) | k);
            const uint2 v = *(const uint2*)(nb + (size_t)idx * C_OUT + o4);
            m0 = fmaxf(m0, __uint_as_float(v.x << 16));
            m1 = fmaxf(m1, __uint_as_float(v.x & 0xffff0000u));
            m2 = fmaxf(m2, __uint_as_float(v.y << 16));
            m3 = fmaxf(m3, __uint_as_float(v.y & 0xffff0000u));
        }

        const int nl = rbl + sub;           // in-place: own cells only
        sm[nl][o4 + 0] = fmaxf(cv.x + m0, 0.f);   // relu(max)==max(relu)
        sm[nl][o4 + 1] = fmaxf(cv.y + m1, 0.f);
        sm[nl][o4 + 2] = fmaxf(cv.z + m2, 0.f);
        sm[nl][o4 + 3] = fmaxf(cv.w + m3, 0.f);
    }
    __syncthreads();

    // ---- transposed coalesced store ----
    float* ob = out + (size_t)b * C_OUT * N_PTS + n0;
    const int nn = lane & 31;
    const int oh = lane >> 5;
#pragma unroll
    for (int j = 0; j < 8; ++j) {
        const int o = wv * 16 + j * 2 + oh;
        ob[(size_t)o * N_PTS + nn] = sm[nn][o];   // 2x128B segments
    }
}

// ---------------------------------------------------------------------------
extern "C" void kernel_launch(void* const* d_in, const int* in_sizes, int n_in,
                              void* d_out, int out_size, void* d_ws, size_t ws_size,
                              hipStream_t stream)
{
    const float* x    = (const float*)d_in[0];
    const int*   eidx = (const int*)d_in[1];    // int64 in ref -> int32 here
    const float* w    = (const float*)d_in[2];  // (64, 128)
    const float* bias = (const float*)d_in[3];  // (64,)
    float*       out  = (float*)d_out;          // (8, 64, 64, 64) f32

    unsigned short* nbuf = (unsigned short*)d_ws;            // 4 MiB
    int*            ctr  = (int*)(nbuf + (size_t)ROWS * C_OUT);

    hipMemsetAsync(ctr, 0, B_SZ * sizeof(int), stream);      // graph-legal
    fused_kernel<<<ROWS / 32, 256, 0, stream>>>(x, w, bias, eidx, nbuf, ctr, out);
}

// Round 19
// 17.993 us; speedup vs baseline: 7.2128x; 7.2128x over previous
//
#include <hip/hip_runtime.h>
#include <stdint.h>

#define B_SZ    8
#define N_PTS   4096
#define C_IN    64
#define C_OUT   64
#define KNN     16
#define ROWS    (B_SZ * N_PTS)      // 32768

typedef __attribute__((ext_vector_type(8))) short v8s;   // 8 bf16 (4 VGPR)
typedef __attribute__((ext_vector_type(4))) float v4f;   // MFMA acc

__device__ inline unsigned short f2bf(float f) {         // RNE f32->bf16
    unsigned int u = __float_as_uint(f);
    return (unsigned short)((u + 0x7FFFu + ((u >> 16) & 1u)) >> 16);
}

__device__ inline v8s pack8(float4 q0, float4 q1) {
    v8s a;
    a[0] = (short)f2bf(q0.x); a[1] = (short)f2bf(q0.y);
    a[2] = (short)f2bf(q0.z); a[3] = (short)f2bf(q0.w);
    a[4] = (short)f2bf(q1.x); a[5] = (short)f2bf(q1.y);
    a[6] = (short)f2bf(q1.z); a[7] = (short)f2bf(q1.w);
    return a;
}

#define PITCH 68    // 68 % 32 == 4: col-strided frag reads are 2-way (free)

// ---------------------------------------------------------------------------
// Kernel A: nbuf projection (MFMA).  nbuf[r][o] = x[r]·W2[o]  (bf16)
// W2 staged into LDS coalesced (16 KB), frags built from LDS (2-way-free).
// 64 rows/block, 4 waves; wave wv: rows wv*16..+15, all 64 cols.
// ---------------------------------------------------------------------------
__global__ __launch_bounds__(256, 2) void proj_nbuf(
    const float* __restrict__ x,
    const float* __restrict__ w,
    unsigned short* __restrict__ nbuf)
{
    __shared__ float wl2[C_OUT][PITCH];     // 17 KB: W2[col][k]

    const int t     = threadIdx.x;
    const int lane  = t & 63;
    const int wv    = t >> 6;
    const int batch = blockIdx.x & 7;                    // XCD-affine
    const int chunk = blockIdx.x >> 3;                   // 0..63
    const int r0    = batch * N_PTS + chunk * 64 + wv * 16;

    // stage W2: idx -> col=idx>>4, q=(idx&15)*4 ; w[col*128 + 64 + q]
#pragma unroll
    for (int i = 0; i < 4; ++i) {
        const int idx = i * 256 + t;        // 0..1023
        const int col = idx >> 4;
        const int q   = (idx & 15) * 4;
        *(float4*)&wl2[col][q] = *(const float4*)(w + col * 128 + 64 + q);
    }

    const int fc   = lane & 15;
    const int koff = 8 * (lane >> 4);

    // afrag: direct from x (independent of LDS; issues before the barrier)
    const int arow = r0 + fc;
    v8s afrag[2];
#pragma unroll
    for (int ks = 0; ks < 2; ++ks) {
        const float* xp = x + (size_t)arow * C_IN + ks * 32 + koff;
        afrag[ks] = pack8(*(const float4*)xp, *(const float4*)(xp + 4));
    }

    __syncthreads();

    v8s bfrag[4][2];
#pragma unroll
    for (int ct = 0; ct < 4; ++ct) {
        const int col = ct * 16 + fc;
#pragma unroll
        for (int ks = 0; ks < 2; ++ks) {
            const float* p = &wl2[col][ks * 32 + koff];
            bfrag[ct][ks] = pack8(*(const float4*)p, *(const float4*)(p + 4));
        }
    }

    v4f acc[4];
#pragma unroll
    for (int ct = 0; ct < 4; ++ct)
        acc[ct] = (v4f){0.f, 0.f, 0.f, 0.f};

#pragma unroll
    for (int ks = 0; ks < 2; ++ks)
#pragma unroll
        for (int ct = 0; ct < 4; ++ct)
            acc[ct] = __builtin_amdgcn_mfma_f32_16x16x32_bf16(
                afrag[ks], bfrag[ct][ks], acc[ct], 0, 0, 0);

    const int crow0 = r0 + (lane >> 4) * 4;
#pragma unroll
    for (int ct = 0; ct < 4; ++ct)
#pragma unroll
        for (int reg = 0; reg < 4; ++reg)
            nbuf[(size_t)(crow0 + reg) * C_OUT + ct * 16 + fc] =
                f2bf(acc[ct][reg]);
}

// ---------------------------------------------------------------------------
// Kernel B: fused cbuf(MFMA, LDS-only) + gather + max + relu + store.
// (W1-W2) computed during coalesced staging into wld (separate LDS region,
// so x-staging and w-staging overlap under ONE barrier). Rest == r14.
//   out[b][o][n] = relu( cbuf[n][o] + max_k nbuf[idx[n,k]][o] )
// ---------------------------------------------------------------------------
__global__ __launch_bounds__(256, 4) void gather_fused(
    const float* __restrict__ x,
    const float* __restrict__ w,
    const float* __restrict__ bias,
    const int* __restrict__ eidx,
    const unsigned short* __restrict__ nbuf,
    float* __restrict__ out)
{
    __shared__ float wld[C_OUT][PITCH];     // 17 KB: (W1-W2)[col][k]
    __shared__ float sm[32][PITCH];         // 8.5 KB: x -> cbuf -> result

    const int t    = threadIdx.x;
    const int lane = t & 63;
    const int wv   = t >> 6;                // wave 0..3
    const int b    = blockIdx.x & 7;        // batch == XCD
    const int tn   = blockIdx.x >> 3;       // 0..127
    const int n0   = tn * 32;
    const int r0g  = b * N_PTS + n0;

    // ---- prefetch eidx (Phase-C rows wv*8..+7) ----
    const size_t ebase = (size_t)(r0g + wv * 8) * KNN;
    const int pa = eidx[ebase + lane]      & (N_PTS - 1);
    const int pb = eidx[ebase + 64 + lane] & (N_PTS - 1);

    // ---- stage (W1-W2) into wld, coalesced; subtract in flight ----
#pragma unroll
    for (int i = 0; i < 4; ++i) {
        const int idx = i * 256 + t;        // 0..1023
        const int col = idx >> 4;
        const int q   = (idx & 15) * 4;
        const float4 w1 = *(const float4*)(w + col * 128 + q);
        const float4 w2 = *(const float4*)(w + col * 128 + 64 + q);
        *(float4*)&wld[col][q] =
            make_float4(w1.x - w2.x, w1.y - w2.y, w1.z - w2.z, w1.w - w2.w);
    }

    // ---- stage 32 x-rows (8 KB) coalesced (disjoint LDS region) ----
    {
        const float4* xsrc = (const float4*)(x + (size_t)r0g * C_IN);
#pragma unroll
        for (int i = 0; i < 2; ++i) {
            const int idx = i * 256 + t;
            *(float4*)&sm[idx >> 4][(idx & 15) * 4] = xsrc[idx];
        }
    }
    __syncthreads();

    // ---- Phase B: cbuf tile via MFMA ----
    const int rq   = wv & 1;                // rows rq*16..+15
    const int ch   = wv >> 1;               // cols ch*32..+31
    const int rl0  = rq * 16;
    const int fc   = lane & 15;
    const int koff = 8 * (lane >> 4);

    v8s bC[2][2];
#pragma unroll
    for (int ct = 0; ct < 2; ++ct) {
        const int col = ch * 32 + ct * 16 + fc;
#pragma unroll
        for (int ks = 0; ks < 2; ++ks) {
            const float* p = &wld[col][ks * 32 + koff];
            bC[ct][ks] = pack8(*(const float4*)p, *(const float4*)(p + 4));
        }
    }

    const int rl = rl0 + fc;
    v8s af[2];
#pragma unroll
    for (int ks = 0; ks < 2; ++ks) {
        const float* xp = &sm[rl][ks * 32 + koff];
        af[ks] = pack8(*(const float4*)xp, *(const float4*)(xp + 4));
    }

    v4f acc[2];
#pragma unroll
    for (int ct = 0; ct < 2; ++ct) {
        const float bv = bias[ch * 32 + ct * 16 + fc];
        acc[ct] = (v4f){bv, bv, bv, bv};
    }
#pragma unroll
    for (int ks = 0; ks < 2; ++ks)
#pragma unroll
        for (int ct = 0; ct < 2; ++ct)
            acc[ct] = __builtin_amdgcn_mfma_f32_16x16x32_bf16(
                af[ks], bC[ct][ks], acc[ct], 0, 0, 0);

    __syncthreads();                        // all af reads from sm done

    const int orow = rl0 + (lane >> 4) * 4;
#pragma unroll
    for (int ct = 0; ct < 2; ++ct)
#pragma unroll
        for (int reg = 0; reg < 4; ++reg)
            sm[orow + reg][ch * 32 + ct * 16 + fc] = acc[ct][reg];

    __syncthreads();                        // cbuf tile complete

    // ---- Phase C: gather + max + relu (wave wv: rows wv*8..+7) ----
    const unsigned short* nb = nbuf + (size_t)b * N_PTS * C_OUT;
    const int o4  = fc * 4;
    const int sub = lane >> 4;

#pragma unroll
    for (int i = 0; i < 2; ++i) {
        const int rbl   = wv * 8 + i * 4;
        const int myidx = (i == 0) ? pa : pb;

        const float4 cv = *(const float4*)&sm[rbl + sub][o4];

        float m0 = -1e30f, m1 = -1e30f, m2 = -1e30f, m3 = -1e30f;
#pragma unroll
        for (int k = 0; k < KNN; ++k) {
            const int idx = __shfl(myidx, (lane & 48) | k);
            const uint2 v = *(const uint2*)(nb + (size_t)idx * C_OUT + o4);
            m0 = fmaxf(m0, __uint_as_float(v.x << 16));
            m1 = fmaxf(m1, __uint_as_float(v.x & 0xffff0000u));
            m2 = fmaxf(m2, __uint_as_float(v.y << 16));
            m3 = fmaxf(m3, __uint_as_float(v.y & 0xffff0000u));
        }

        const int nl = rbl + sub;           // in-place: own cells only
        sm[nl][o4 + 0] = fmaxf(cv.x + m0, 0.f);   // relu(max)==max(relu)
        sm[nl][o4 + 1] = fmaxf(cv.y + m1, 0.f);
        sm[nl][o4 + 2] = fmaxf(cv.z + m2, 0.f);
        sm[nl][o4 + 3] = fmaxf(cv.w + m3, 0.f);
    }
    __syncthreads();

    // ---- transposed coalesced store ----
    float* ob = out + (size_t)b * C_OUT * N_PTS + n0;
    const int nn = lane & 31;
    const int oh = lane >> 5;
#pragma unroll
    for (int j = 0; j < 8; ++j) {
        const int o = wv * 16 + j * 2 + oh;
        ob[(size_t)o * N_PTS + nn] = sm[nn][o];   // 2x128B segments
    }
}

// ---------------------------------------------------------------------------
extern "C" void kernel_launch(void* const* d_in, const int* in_sizes, int n_in,
                              void* d_out, int out_size, void* d_ws, size_t ws_size,
                              hipStream_t stream)
{
    const float* x    = (const float*)d_in[0];
    const int*   eidx = (const int*)d_in[1];    // int64 in ref -> int32 here
    const float* w    = (const float*)d_in[2];  // (64, 128)
    const float* bias = (const float*)d_in[3];  // (64,)
    float*       out  = (float*)d_out;          // (8, 64, 64, 64) f32

    unsigned short* nbuf = (unsigned short*)d_ws;   // 4 MiB

    proj_nbuf<<<ROWS / 64, 256, 0, stream>>>(x, w, nbuf);
    gather_fused<<<ROWS / 32, 256, 0, stream>>>(x, w, bias, eidx, nbuf, out);
}